// Round 1
// baseline (365.022 us; speedup 1.0000x reference)
//
#include <hip/hip_runtime.h>
#include <math.h>

// Problem constants
#define NPX   1048576      // 1024*1024
#define TD    1025         // tex_eval spatial dim
#define PW    35           // patch width (cells) for 32-wide tile
#define PH    19           // patch height (cells) for 16-tall tile
#define DPAD  1028         // padded input spatial dim (rows -2..1025 -> 0..1027)
#define ROWB  65792        // DPAD*32*2 bytes per padded row
// ws layout: [0, 16KB)            ffrag_g fp16 [kk][lane][8] (MFMA B-frag order)
//            [48KB, +33.62MB)     tex     fp16 [y][x][c]  (TD*TD*16)
//            [DP_OFF, +67.63MB)   Dp      fp16 [1028][1028][32] zero-padded CL
#define DP_OFF 33673216

typedef _Float16 half8 __attribute__((ext_vector_type(8)));
typedef _Float16 half4 __attribute__((ext_vector_type(4)));
typedef float    f32x4 __attribute__((ext_vector_type(4)));

__device__ __forceinline__ void load_lds16(const void* g, void* lds) {
    __builtin_amdgcn_global_load_lds(
        (const __attribute__((address_space(1))) void*)g,
        (__attribute__((address_space(3))) void*)lds, 16, 0, 0);
}

// ------- Stage 1: MLP -> MFMA B-fragment-ordered fp16 filter (fused) ---------
// Each of 32 blocks redundantly computes layers 1-2 (tiny), then its 256
// layer-3 outputs, writing each tanh directly into MFMA B-fragment order:
// ffrag_g[(kk*64 + (ic>>3)*16 + oc)*8 + (ic&7)],  o = oc*512 + ic*16 + kk.
// NOTE: this per-lane packing is simultaneously the A-fragment packing for the
// operand-swapped MFMA in stage 2 (A[m=l&15][k=(l>>4)*8+i] == same lane data).
__global__ __launch_bounds__(256) void mlp_kernel(
    const float* __restrict__ expr,
    const float* __restrict__ W1, const float* __restrict__ b1,
    const float* __restrict__ W2, const float* __restrict__ b2,
    const float* __restrict__ W3, const float* __restrict__ b3,
    _Float16* __restrict__ ffrag_g)
{
    __shared__ float sx[76];
    __shared__ float sh1[128];
    __shared__ float sh2[64];
    int t = threadIdx.x;
    if (t < 76) sx[t] = expr[t];
    __syncthreads();
    if (t < 128) {
        float a = b1[t];
        const float* w = W1 + t * 76;
        #pragma unroll 4
        for (int i = 0; i < 76; ++i) a += sx[i] * w[i];
        sh1[t] = a >= 0.f ? a : 0.02f * a;
    }
    __syncthreads();
    if (t < 64) {
        float a = b2[t];
        const float* w = W2 + t * 128;
        #pragma unroll 4
        for (int i = 0; i < 128; ++i) a += sh1[i] * w[i];
        sh2[t] = a >= 0.f ? a : 0.02f * a;
    }
    __syncthreads();
    int o = blockIdx.x * 256 + t;            // 0..8191
    float a = b3[o];
    const float* w = W3 + o * 64;
    #pragma unroll 4
    for (int i = 0; i < 64; ++i) a += sh2[i] * w[i];
    a = tanhf(a);
    int oc = o >> 9;                          // o / 512
    int ic = (o >> 4) & 31;
    int kk = o & 15;                          // ky*4+kx
    ffrag_g[(size_t)(kk * 64 + (ic >> 3) * 16 + oc) * 8 + (ic & 7)] = (_Float16)a;
}

// ------ Stage 1c: repack data fp32 NCHW -> zero-padded fp16 channel-last -----
// Dp[Y][X][ic], Y = y+2, X = x+2, zeros outside [0,1024). Fully coalesced via
// XOR-swizzled LDS transpose (conflict-free writes AND reads).
__global__ __launch_bounds__(256) void repack_kernel(
    const float* __restrict__ data, _Float16* __restrict__ Dp)
{
    __shared__ _Float16 s[256 * 32];          // 16 KB
    int tid = threadIdx.x;
    int Y = blockIdx.y;
    int X = blockIdx.x * 256 + tid;
    int y = Y - 2, x = X - 2;
    bool ok = ((unsigned)y < 1024u) && ((unsigned)x < 1024u);
    const float* dp = data + ((size_t)y << 10) + x;

    float v[32];
    #pragma unroll
    for (int j = 0; j < 32; ++j) v[j] = 0.f;
    if (ok) {
        #pragma unroll
        for (int j = 0; j < 32; ++j) v[j] = __builtin_nontemporal_load(&dp[(size_t)j * NPX]);
    }
    #pragma unroll
    for (int g = 0; g < 4; ++g) {
        half8 h;
        #pragma unroll
        for (int j = 0; j < 8; ++j) h[j] = (_Float16)v[g * 8 + j];
        int chunk = tid * 4 + g;
        int sw = chunk ^ ((chunk >> 3) & 7);  // spread banks
        *(half8*)((char*)s + sw * 16) = h;
    }
    __syncthreads();
    char* rowbase = (char*)Dp + (size_t)Y * ROWB + blockIdx.x * 16384;
    int lim = ROWB - blockIdx.x * 16384;
    #pragma unroll
    for (int i = 0; i < 4; ++i) {
        int off = tid * 16 + i * 4096;
        if (off < lim) {
            int chunk = tid + i * 256;
            int sw = chunk ^ ((chunk >> 3) & 7);
            *(uint4*)(rowbase + off) = *(uint4*)((char*)s + sw * 16);
        }
    }
}

// ------------- Stage 2: implicit-GEMM conv via 16x16x32 f16 MFMA -------------
// Tile 32(x) x 16(y). Patch rows DMA'd via global_load_lds (contiguous 2240 B
// runs in channel-last Dp). Filter fragments live in registers.
//
// R1 changes vs previous version:
//  (a) LDS 16B-chunk XOR swizzle (c ^= (c>>3)&7, involution, row-local):
//      breaks the 64B-stride quarter-phase bank aliasing of the A-frag
//      ds_read_b128 (was ~4 extra cyc/read, 4.39M conflicts). Applied on the
//      global SOURCE address of global_load_lds (dest stays linear, rule 21)
//      and on the LDS read address.
//  (b) Operand-swapped MFMA: mfma(bfrag, af, acc). A/B fragments hold
//      identical per-lane data under role swap, so data movement is unchanged,
//      but C/D becomes col=pixel, row=channel -> each lane's 4 acc values are
//      4 contiguous channels of one pixel -> one 8B packed store per tile,
//      512 B contiguous per wave instruction (was 2B scatter, 5.2x write amp).
__global__ __launch_bounds__(256, 3) void conv_mfma_kernel(
    const _Float16* __restrict__ Dp,         // [1028][1028][32] fp16
    const _Float16* __restrict__ ffrag_g,    // [16][64][8] fp16
    _Float16* __restrict__ tex)              // [1025][1025][16] fp16
{
    __shared__ __attribute__((aligned(128))) _Float16 sp[PH * PW * 32]; // 42,560 B

    int tid = threadIdx.x;
    int l = tid & 63, w = tid >> 6;
    int ox0 = blockIdx.x * 32;
    int oy0 = blockIdx.y * 16;

    // filter fragments -> registers (64 VGPR), L2-hot
    half8 bfrag[16];
    #pragma unroll
    for (int kk = 0; kk < 16; ++kk)
        bfrag[kk] = *(const half8*)&ffrag_g[kk * 512 + l * 8];

    // stage patch: wave w DMAs rows w, w+4, ... ; 2240 B per row as 1024+1024+192.
    // LDS dest is linear (lane*16); the chunk swizzle is realized by permuting
    // the per-lane GLOBAL source chunk (involution, so dest p holds logical s(p)).
    // Edge tiles: clamp the GLOBAL source address only — garbage lands in
    // logical cells consumed solely by discarded (oy/px > 1024) outputs.
    int lsw = l ^ ((l >> 3) & 7);            // source-chunk permutation
    for (int r = w; r < PH; r += 4) {
        int gy = min(oy0 + r, DPAD - 1);
        const char* grow = (const char*)Dp + (size_t)gy * ROWB;
        _Float16* lrow = sp + r * (PW * 32);
        #pragma unroll
        for (int c = 0; c < 3; ++c) {
            int off = ox0 * 64 + c * 1024 + lsw * 16;
            off = min(off, ROWB - 16);
            if (c < 2 || l < 12)             // lsw permutes within 0..11 for l<12
                load_lds16(grow + off, (char*)lrow + c * 1024);
        }
    }
    __syncthreads();

    int lane15 = l & 15;
    int q = l >> 4;

    // Precompute swizzled A-frag byte offsets. Logical chunk within a row is
    // cin = pcInRow*4 + q = (t&1)*64 + (kx*4 + lane15*4 + q); the (t&1)*64 term
    // commutes with the XOR (bit 6 untouched), so only 4 values are needed.
    int u = lane15 * 4 + q;
    int sv[4];
    #pragma unroll
    for (int kx = 0; kx < 4; ++kx) {
        int vch = kx * 4 + u;
        sv[kx] = (vch ^ ((vch >> 3) & 7)) * 16;    // byte offset in row
    }

    f32x4 acc[8];
    #pragma unroll
    for (int t = 0; t < 8; ++t) acc[t] = (f32x4){0.f, 0.f, 0.f, 0.f};

    // m-tile t: tile row (w*4 + (t>>1)), x half (t&1); lane pixel = lane15
    #pragma unroll 4
    for (int kk = 0; kk < 16; ++kk) {
        int ky = kk >> 2, kx = kk & 3;
        #pragma unroll
        for (int t = 0; t < 8; ++t) {
            const char* ap = (const char*)sp
                + (w * 4 + (t >> 1) + ky) * (PW * 64)  // row * 2240 B
                + (t & 1) * 1024 + sv[kx];
            half8 af = *(const half8*)ap;
            // swapped operands: D col = lane&15 = pixel, row = q*4+reg = channel
            acc[t] = __builtin_amdgcn_mfma_f32_16x16x32_f16(bfrag[kk], af, acc[t], 0, 0, 0);
        }
    }

    // epilogue: lane holds channels q*4..q*4+3 of pixel (ox0+(t&1)*16+lane15).
    // Pack to half4, one 8B store per tile: 512 B contiguous per wave instr.
    #pragma unroll
    for (int t = 0; t < 8; ++t) {
        int oy = oy0 + w * 4 + (t >> 1);
        int px = ox0 + (t & 1) * 16 + lane15;
        if (oy > 1024 || px > 1024) continue;
        half4 hv;
        #pragma unroll
        for (int r = 0; r < 4; ++r) hv[r] = (_Float16)acc[t][r];
        *(half4*)&tex[((size_t)oy * TD + px) * 16 + q * 4] = hv;
    }
}

// ---------------- Stage 3: bilinear grid-sample (border pad) -----------------
// 1 px/thread, minimal VGPR -> max resident waves (gather-latency hiding).
// All 8 texel loads issued before any use; nontemporal uv/out (stream-once).
__global__ __launch_bounds__(256, 6) void sample_kernel(
    const float* __restrict__ uv,            // [2][1024][1024]
    const _Float16* __restrict__ tex,        // [1025][1025][16] fp16
    float* __restrict__ out)                 // [16][1024][1024]
{
    int p = blockIdx.x * 256 + threadIdx.x;  // 0..NPX-1
    float x = __builtin_nontemporal_load(&uv[p]);
    float y = __builtin_nontemporal_load(&uv[NPX + p]);
    float ix = fminf(fmaxf(((x + 1.f) * 1025.f - 1.f) * 0.5f, 0.f), 1024.f);
    float iy = fminf(fmaxf(((y + 1.f) * 1025.f - 1.f) * 0.5f, 0.f), 1024.f);
    float fx0 = floorf(ix), fy0 = floorf(iy);
    float wx = ix - fx0, wy = iy - fy0;
    int x0 = (int)fx0, y0 = (int)fy0;
    int x1 = min(x0 + 1, 1024), y1 = min(y0 + 1, 1024);

    const half8* t00 = (const half8*)(tex + ((size_t)y0 * TD + x0) * 16);
    const half8* t01 = (const half8*)(tex + ((size_t)y0 * TD + x1) * 16);
    const half8* t10 = (const half8*)(tex + ((size_t)y1 * TD + x0) * 16);
    const half8* t11 = (const half8*)(tex + ((size_t)y1 * TD + x1) * 16);

    half8 v0 = t00[0], v1 = t00[1];
    half8 v2 = t01[0], v3 = t01[1];
    half8 v4 = t10[0], v5 = t10[1];
    half8 v6 = t11[0], v7 = t11[1];

    float w00 = (1.f - wx) * (1.f - wy);
    float w01 = wx * (1.f - wy);
    float w10 = (1.f - wx) * wy;
    float w11 = wx * wy;

    #pragma unroll
    for (int c = 0; c < 8; ++c) {
        float r0 = (float)v0[c] * w00 + (float)v2[c] * w01
                 + (float)v4[c] * w10 + (float)v6[c] * w11;
        float r1 = (float)v1[c] * w00 + (float)v3[c] * w01
                 + (float)v5[c] * w10 + (float)v7[c] * w11;
        __builtin_nontemporal_store(r0, &out[(size_t)c * NPX + p]);
        __builtin_nontemporal_store(r1, &out[(size_t)(c + 8) * NPX + p]);
    }
}

extern "C" void kernel_launch(void* const* d_in, const int* in_sizes, int n_in,
                              void* d_out, int out_size, void* d_ws, size_t ws_size,
                              hipStream_t stream) {
    const float* expr = (const float*)d_in[0];
    // d_in[1] = audio_features: unused by the reference
    const float* uv   = (const float*)d_in[2];
    const float* data = (const float*)d_in[3];
    const float* W1   = (const float*)d_in[4];
    const float* b1   = (const float*)d_in[5];
    const float* W2   = (const float*)d_in[6];
    const float* b2   = (const float*)d_in[7];
    const float* W3   = (const float*)d_in[8];
    const float* b3   = (const float*)d_in[9];
    float* out = (float*)d_out;

    _Float16* ffrag_g  = (_Float16*)d_ws;                            // 16 KB
    _Float16* tex      = (_Float16*)((char*)d_ws + 49152);           // 33.62 MB
    _Float16* Dp       = (_Float16*)((char*)d_ws + DP_OFF);          // 67.63 MB

    mlp_kernel<<<32, 256, 0, stream>>>(expr, W1, b1, W2, b2, W3, b3, ffrag_g);
    repack_kernel<<<dim3(5, DPAD), 256, 0, stream>>>(data, Dp);
    conv_mfma_kernel<<<dim3(33, 65), 256, 0, stream>>>(Dp, ffrag_g, tex);
    sample_kernel<<<NPX / 256, 256, 0, stream>>>(uv, tex, out);
}